// Round 4
// baseline (7104.526 us; speedup 1.0000x reference)
//
#include <hip/hip_runtime.h>
#include <hip/hip_fp16.h>

// LSTM: B=32, T=4096, D=256, H=256, gates=1024 (i,g,f,o), HORIZON=24
// Pipeline: prep_x (f32->bf16) ; prep_w (Wx transpose->bf16, Wh pack->f16 pairs) ;
//           prep_q (reorder tail-B weight quads for per-step streaming) ;
//           xproj MFMA GEMM -> gates_x f16 [B][T][1024] (bias + forget+1 folded) ;
//           scan: 32 blocks x 512 thr. Weight residency sized to the TRUE budget
//             (2 waves/SIMD -> 256 unified regs/wave): 104 pairs x 2 cols = 208 VGPRs
//             resident (r0/r3's 114 overflowed -> spill restores ~1400 cyc/step).
//             Pairs 104..117 from LDS quads, 118..127 streamed from global (L1-hot).
//           head: two tiny FCs.

#define T_STEPS 4096
#define BATCH 32
#define RPAIRS 104   // f16 row-pairs of W_h per column held in VGPRs
#define LQUADS 7     // LDS tail: pairs 104..117 (14 pairs, 57 KB)
#define GQUADS 5     // global-streamed tail: pairs 118..127 (10 pairs)

typedef short short8 __attribute__((ext_vector_type(8)));
typedef float f32x4 __attribute__((ext_vector_type(4)));
typedef _Float16 half2_t __attribute__((ext_vector_type(2)));

__device__ inline unsigned short f32_to_bf16(float f) {
  unsigned int u = __builtin_bit_cast(unsigned int, f);
  u = u + 0x7fffu + ((u >> 16) & 1u);   // RNE
  return (unsigned short)(u >> 16);
}

__device__ inline float fdot2f(unsigned int w, unsigned int h, float acc) {
#if __has_builtin(__builtin_amdgcn_fdot2)
  return __builtin_amdgcn_fdot2(__builtin_bit_cast(half2_t, w),
                                __builtin_bit_cast(half2_t, h), acc, false);
#else
  half2_t a = __builtin_bit_cast(half2_t, w);
  half2_t b = __builtin_bit_cast(half2_t, h);
  acc += (float)a.x * (float)b.x;
  acc += (float)a.y * (float)b.y;
  return acc;
#endif
}

// ---------------- prep: x f32 -> bf16 ----------------
__global__ void k_prep_x(const float4* __restrict__ x, unsigned short* __restrict__ xbf, int n4) {
  int i = blockIdx.x * blockDim.x + threadIdx.x;
  if (i >= n4) return;
  float4 v = x[i];
  ushort4 o;
  o.x = f32_to_bf16(v.x); o.y = f32_to_bf16(v.y);
  o.z = f32_to_bf16(v.z); o.w = f32_to_bf16(v.w);
  ((ushort4*)xbf)[i] = o;
}

// ---------------- prep: weights ----------------
// WxT[n][k] = bf16(W_lstm[k][n]) for k<256  (pre-transposed so xproj B-frags are contiguous)
// Whp[p][c] = pack(f16(W_lstm[256+2p][c]), f16(W_lstm[257+2p][c]))  p in [0,128)
__global__ void k_prep_w(const float* __restrict__ W, unsigned short* __restrict__ WxT,
                         unsigned int* __restrict__ Whp) {
  int i = blockIdx.x * blockDim.x + threadIdx.x;
  if (i < 256 * 1024) {
    int n = i >> 8, k = i & 255;
    WxT[i] = f32_to_bf16(W[k * 1024 + n]);
  } else {
    int j = i - 256 * 1024;   // j in [0, 131072)
    int p = j >> 10, c = j & 1023;
    _Float16 lo = (_Float16)W[(256 + 2 * p) * 1024 + c];
    _Float16 hi = (_Float16)W[(257 + 2 * p) * 1024 + c];
    Whp[j] = (unsigned int)__builtin_bit_cast(unsigned short, lo) |
             ((unsigned int)__builtin_bit_cast(unsigned short, hi) << 16);
  }
}

// ---------------- prep: tail-B quads for streaming ----------------
// Whq4[i*512+tid] = {wA(118+2i), wB(118+2i), wA(119+2i), wB(119+2i)} for thread tid (cols 2t,2t+1)
__global__ void k_prep_q(const unsigned int* __restrict__ Whp, uint4* __restrict__ Whq4) {
  int j = blockIdx.x * blockDim.x + threadIdx.x;
  if (j >= GQUADS * 512) return;
  int i = j >> 9, tid = j & 511, cA = 2 * tid;
  int p = RPAIRS + 2 * LQUADS + 2 * i;   // 118 + 2i
  uint2 u = *(const uint2*)(Whp + (size_t)p * 1024 + cA);
  uint2 v = *(const uint2*)(Whp + (size_t)(p + 1) * 1024 + cA);
  Whq4[j] = uint4{u.x, u.y, v.x, v.y};
}

// ---------------- xproj: gates_x = x @ Wx + b (+1 on f-gate) ----------------
// M=131072, N=1024, K=256. bf16 MFMA 16x16x32, 64x64 tile per 256-thr block, direct global loads.
__global__ __launch_bounds__(256) void k_xproj(const unsigned short* __restrict__ A,
                                               const unsigned short* __restrict__ BT,
                                               const float* __restrict__ bias,
                                               __half* __restrict__ G) {
  int bm = blockIdx.x * 64;
  int bn = blockIdx.y * 64;
  int lane = threadIdx.x & 63, wave = threadIdx.x >> 6;
  int wm = (wave & 1) * 32, wn = (wave >> 1) * 32;
  int q = lane >> 4, l16 = lane & 15;

  f32x4 acc[2][2] = {};
  const unsigned short* Ab = A + (size_t)(bm + wm + l16) * 256 + q * 8;
  const unsigned short* Bb = BT + (size_t)(bn + wn + l16) * 256 + q * 8;

#pragma unroll
  for (int kk = 0; kk < 8; ++kk) {
    short8 a0 = *(const short8*)(Ab + kk * 32);
    short8 a1 = *(const short8*)(Ab + 16 * 256 + kk * 32);
    short8 b0 = *(const short8*)(Bb + kk * 32);
    short8 b1 = *(const short8*)(Bb + 16 * 256 + kk * 32);
    acc[0][0] = __builtin_amdgcn_mfma_f32_16x16x32_bf16(a0, b0, acc[0][0], 0, 0, 0);
    acc[0][1] = __builtin_amdgcn_mfma_f32_16x16x32_bf16(a0, b1, acc[0][1], 0, 0, 0);
    acc[1][0] = __builtin_amdgcn_mfma_f32_16x16x32_bf16(a1, b0, acc[1][0], 0, 0, 0);
    acc[1][1] = __builtin_amdgcn_mfma_f32_16x16x32_bf16(a1, b1, acc[1][1], 0, 0, 0);
  }

#pragma unroll
  for (int nt = 0; nt < 2; ++nt) {
    int col = bn + wn + nt * 16 + l16;
    float bv = bias[col] + ((col >= 512 && col < 768) ? 1.0f : 0.0f);
#pragma unroll
    for (int mt = 0; mt < 2; ++mt) {
#pragma unroll
      for (int r = 0; r < 4; ++r) {
        int row = bm + wm + mt * 16 + q * 4 + r;
        G[(size_t)row * 1024 + col] = __float2half_rn(acc[mt][nt][r] + bv);
      }
    }
  }
}

// ---------------- recurrent scan ----------------
// 32 blocks (one per batch element) x 512 threads. Thread t owns gate cols 2t, 2t+1.
__global__ __launch_bounds__(512, 2) void k_scan(const unsigned int* __restrict__ Whp,
                                                 const uint4* __restrict__ Whq4,
                                                 const __half* __restrict__ G,
                                                 float* __restrict__ hfin) {
  __shared__ __align__(16) unsigned int h2[128];        // h packed as f16 pairs
  __shared__ float gates[1024];
  __shared__ __align__(16) uint4 WLq4[LQUADS * 512];    // LDS tail, [i][tid]

  int tid = threadIdx.x;
  int b = blockIdx.x;
  int cA = 2 * tid;

  // stage LDS tail: WLq4[i*512+tid] = {wA[104+2i], wB[104+2i], wA[105+2i], wB[105+2i]}
#pragma unroll
  for (int i = 0; i < LQUADS; ++i) {
    int p = RPAIRS + 2 * i;
    uint2 u = *(const uint2*)(Whp + (size_t)p * 1024 + cA);
    uint2 v = *(const uint2*)(Whp + (size_t)(p + 1) * 1024 + cA);
    WLq4[i * 512 + tid] = uint4{u.x, u.y, v.x, v.y};
  }

  // register-resident W_h: pairs 0..103 for each of the 2 adjacent columns (208 VGPRs)
  unsigned int wA[RPAIRS], wB[RPAIRS];
#pragma unroll
  for (int p = 0; p < RPAIRS; ++p) {
    uint2 w = *(const uint2*)(Whp + p * 1024 + cA);
    wA[p] = w.x; wB[p] = w.y;
  }
  if (tid < 128) h2[tid] = 0u;   // h0 = 0
  float c_state = 0.0f;

  const unsigned short* gp = (const unsigned short*)(G + (size_t)b * T_STEPS * 1024);
  unsigned int gx_next = *(const unsigned int*)(gp + cA);   // step 0, cols 2t,2t+1
  __syncthreads();

  const uint4* h2q = (const uint4*)h2;
  const uint4* wq = Whq4 + tid;

  for (int step = 0; step < T_STEPS; ++step) {
    unsigned int gx_cur = gx_next;
    if (step + 1 < T_STEPS)
      gx_next = *(const unsigned int*)(gp + (size_t)(step + 1) * 1024 + cA);

    half2_t gxh = __builtin_bit_cast(half2_t, gx_cur);
    float accA0 = (float)gxh.x, accB0 = (float)gxh.y;
    float accA1 = 0.0f, accB1 = 0.0f;

    // chunks 0..25: pairs 0..103, weights in VGPR, h via uniform b128 broadcast
#pragma unroll
    for (int ch = 0; ch < 26; ++ch) {
      uint4 hh = h2q[ch];
      accA0 = fdot2f(wA[ch * 4 + 0], hh.x, accA0); accB0 = fdot2f(wB[ch * 4 + 0], hh.x, accB0);
      accA1 = fdot2f(wA[ch * 4 + 1], hh.y, accA1); accB1 = fdot2f(wB[ch * 4 + 1], hh.y, accB1);
      accA0 = fdot2f(wA[ch * 4 + 2], hh.z, accA0); accB0 = fdot2f(wB[ch * 4 + 2], hh.z, accB0);
      accA1 = fdot2f(wA[ch * 4 + 3], hh.w, accA1); accB1 = fdot2f(wB[ch * 4 + 3], hh.w, accB1);
    }

    // chunks 26..28: pairs 104..115 from LDS quads [0..5]
#pragma unroll
    for (int t = 0; t < 3; ++t) {
      uint4 hh = h2q[26 + t];
      uint4 q0 = WLq4[(2 * t) * 512 + tid];
      uint4 q1 = WLq4[(2 * t + 1) * 512 + tid];
      accA0 = fdot2f(q0.x, hh.x, accA0); accB0 = fdot2f(q0.y, hh.x, accB0);
      accA1 = fdot2f(q0.z, hh.y, accA1); accB1 = fdot2f(q0.w, hh.y, accB1);
      accA0 = fdot2f(q1.x, hh.z, accA0); accB0 = fdot2f(q1.y, hh.z, accB0);
      accA1 = fdot2f(q1.z, hh.w, accA1); accB1 = fdot2f(q1.w, hh.w, accB1);
    }
    { // chunk 29: pairs 116,117 (LDS quad 6) + 118,119 (global quad 0)
      uint4 hh = h2q[29];
      uint4 q0 = WLq4[6 * 512 + tid];
      uint4 q1 = wq[0 * 512];
      accA0 = fdot2f(q0.x, hh.x, accA0); accB0 = fdot2f(q0.y, hh.x, accB0);
      accA1 = fdot2f(q0.z, hh.y, accA1); accB1 = fdot2f(q0.w, hh.y, accB1);
      accA0 = fdot2f(q1.x, hh.z, accA0); accB0 = fdot2f(q1.y, hh.z, accB0);
      accA1 = fdot2f(q1.z, hh.w, accA1); accB1 = fdot2f(q1.w, hh.w, accB1);
    }
    // chunks 30..31: pairs 120..127 from global quads 1..4 (L1-hot, step-invariant)
#pragma unroll
    for (int t = 0; t < 2; ++t) {
      uint4 hh = h2q[30 + t];
      uint4 q0 = wq[(1 + 2 * t) * 512];
      uint4 q1 = wq[(2 + 2 * t) * 512];
      accA0 = fdot2f(q0.x, hh.x, accA0); accB0 = fdot2f(q0.y, hh.x, accB0);
      accA1 = fdot2f(q0.z, hh.y, accA1); accB1 = fdot2f(q0.w, hh.y, accB1);
      accA0 = fdot2f(q1.x, hh.z, accA0); accB0 = fdot2f(q1.y, hh.z, accB0);
      accA1 = fdot2f(q1.z, hh.w, accA1); accB1 = fdot2f(q1.w, hh.w, accB1);
    }

    *(float2*)(gates + cA) = float2{accA0 + accA1, accB0 + accB1};
    __syncthreads();

    if (tid < 256) {
      float gi = gates[tid];
      float gg = gates[tid + 256];
      float gf = gates[tid + 512];   // +1 already folded in
      float go = gates[tid + 768];
      float si = 1.0f / (1.0f + __expf(-gi));
      float sf = 1.0f / (1.0f + __expf(-gf));
      float so = 1.0f / (1.0f + __expf(-go));
      float eg = __expf(2.0f * gg);
      float tg = 1.0f - 2.0f / (eg + 1.0f);    // tanh, overflow-safe
      c_state = sf * c_state + si * tg;
      float ec = __expf(2.0f * c_state);
      float tc = 1.0f - 2.0f / (ec + 1.0f);
      float h = so * tc;
      ((__half*)h2)[tid] = __float2half_rn(h);
      if (step == T_STEPS - 1) hfin[b * 256 + tid] = h;
    }
    __syncthreads();
  }
}

// ---------------- head: out = (h@Wfc+bfc)@Wout+bout ----------------
__global__ void k_head(const float* __restrict__ hfin, const float* __restrict__ Wfc,
                       const float* __restrict__ bfc, const float* __restrict__ Wout,
                       const float* __restrict__ bout, float* __restrict__ out) {
  __shared__ float hs[256];
  __shared__ float fcs[256];
  int b = blockIdx.x, j = threadIdx.x;
  hs[j] = hfin[b * 256 + j];
  __syncthreads();
  float acc = bfc[j];
#pragma unroll 8
  for (int k = 0; k < 256; ++k) acc += hs[k] * Wfc[k * 256 + j];
  fcs[j] = acc;
  __syncthreads();
  if (j < 24) {
    float a2 = bout[j];
#pragma unroll 8
    for (int k = 0; k < 256; ++k) a2 += fcs[k] * Wout[k * 24 + j];
    out[b * 24 + j] = a2;
  }
}

extern "C" void kernel_launch(void* const* d_in, const int* in_sizes, int n_in,
                              void* d_out, int out_size, void* d_ws, size_t ws_size,
                              hipStream_t stream) {
  const float* x    = (const float*)d_in[0];
  const float* Wl   = (const float*)d_in[1];
  const float* bl   = (const float*)d_in[2];
  const float* Wfc  = (const float*)d_in[3];
  const float* bfc  = (const float*)d_in[4];
  const float* Wout = (const float*)d_in[5];
  const float* bout = (const float*)d_in[6];
  float* out = (float*)d_out;

  char* ws = (char*)d_ws;
  // ws layout (bytes), total ~321 MB
  unsigned short* xbf = (unsigned short*)ws;                    //  67108864  x as bf16
  unsigned short* WxT = (unsigned short*)(ws + 67108864);       //    524288  Wx^T bf16 [1024][256]
  unsigned int*   Whp = (unsigned int*)(ws + 67633152);         //    524288  Wh f16 pairs [128][1024]
  __half*         G   = (__half*)(ws + 68157440);               // 268435456  gates_x f16 [B][T][1024]
  float*          hfin= (float*)(ws + 336592896);               //     32768  final h f32
  uint4*          Whq4= (uint4*)(ws + 336625664);               //     40960  tail-B quads [5][512]

  k_prep_x<<<32768, 256, 0, stream>>>((const float4*)x, xbf, 8388608);
  k_prep_w<<<1536, 256, 0, stream>>>(Wl, WxT, Whp);
  k_prep_q<<<10, 256, 0, stream>>>(Whp, Whq4);
  dim3 gx(2048, 16, 1);
  k_xproj<<<gx, 256, 0, stream>>>(xbf, WxT, bl, G);
  k_scan<<<32, 512, 0, stream>>>(Whp, Whq4, G, hfin);
  k_head<<<32, 256, 0, stream>>>(hfin, Wfc, bfc, Wout, bout, out);
}